// Round 1
// baseline (478.151 us; speedup 1.0000x reference)
//
#include <hip/hip_runtime.h>
#include <hip/hip_bf16.h>
#include <math.h>

// Problem constants
#define BB 8
#define NN 1024
#define SS 64
#define VCC 8
#define EE 64
#define HH 4
#define HDD 16

// d_out layout: s (B*N*S=524288) | v (B*N*VC*3=196608) | pd (B*N*N=8388608)
#define OUT_S_OFF 0
#define OUT_V_OFF 524288
#define OUT_PD_OFF 720896

// 3-adic valuation capped at 10, zero for d==0
__device__ __forceinline__ int val3(int d) {
    int c = 0;
    unsigned ud = (unsigned)d;
    c += (ud % 3u == 0u);
    c += (ud % 9u == 0u);
    c += (ud % 27u == 0u);
    c += (ud % 81u == 0u);
    c += (ud % 243u == 0u);
    c += (ud % 729u == 0u);
    c += (ud % 2187u == 0u);
    c += (ud % 6561u == 0u);
    c += (ud % 19683u == 0u);
    c += (ud % 59049u == 0u);
    return d > 0 ? c : 0;
}

// ---------------- Kernel A: pd matrix + row means ----------------
__global__ void pd_kernel(const float* __restrict__ coords,
                          float* __restrict__ pd_out,
                          float* __restrict__ pdmean) {
    const int row = blockIdx.x;           // b*N + i
    const int b = row >> 10;
    const int i = row & 1023;
    const int tid = threadIdx.x;
    const float* cb = coords + (size_t)b * NN * 3;
    const float cx = cb[i * 3 + 0];
    const float cy = cb[i * 3 + 1];
    const float cz = cb[i * 3 + 2];
    float* prow = pd_out + (size_t)row * NN;

    // 3^(-cnt/3) = exp2(-cnt * log2(3)/3)
    const float kLog2_3_over3 = 0.5283208335737187f;

    float lsum = 0.0f;
    for (int j = tid; j < NN; j += 256) {
        float dx = cx - cb[j * 3 + 0];
        float dy = cy - cb[j * 3 + 1];
        float dz = cz - cb[j * 3 + 2];
        int d0 = (int)(fabsf(dx) * 1000.0f);
        int d1 = (int)(fabsf(dy) * 1000.0f);
        int d2 = (int)(fabsf(dz) * 1000.0f);
        int cnt = val3(d0) + val3(d1) + val3(d2);
        float p = exp2f(-(float)cnt * kLog2_3_over3);
        prow[j] = p;
        lsum += p;
    }
    // block reduce sum (4 waves)
    __shared__ float red[4];
    float x = lsum;
    #pragma unroll
    for (int off = 32; off > 0; off >>= 1) x += __shfl_xor(x, off, 64);
    if ((tid & 63) == 0) red[tid >> 6] = x;
    __syncthreads();
    if (tid == 0) pdmean[row] = (red[0] + red[1] + red[2] + red[3]) * (1.0f / 1024.0f);
}

__device__ __forceinline__ float silu_f(float x) {
    return x / (1.0f + expf(-x));
}
__device__ __forceinline__ float sigmoid_f(float x) {
    return 1.0f / (1.0f + expf(-x));
}

// ---------------- Kernel B: encoder MLP + 3 GVP layers ----------------
__global__ void gvp_kernel(const float* __restrict__ s_in,
                           const float* __restrict__ v_in,
                           const float* __restrict__ enc_w1,
                           const float* __restrict__ enc_b1,
                           const float* __restrict__ enc_w2,
                           const float* __restrict__ enc_b2,
                           const float* __restrict__ scal_w,
                           const float* __restrict__ scal_b,
                           const float* __restrict__ vec_w,
                           const float* __restrict__ gate_w,
                           const float* __restrict__ gate_b,
                           const float* __restrict__ pdmean,
                           float* __restrict__ s_gvp,
                           float* __restrict__ v_out) {
    const int row = blockIdx.x;   // b*N + n
    const int tid = threadIdx.x;  // 128 threads

    __shared__ float sc[72];      // [s | vn]
    __shared__ float vb[24];      // current v (8 channels x 3)
    __shared__ float vt[24];      // raw v_new
    __shared__ float g[8];        // gate
    __shared__ float hid[16];     // encoder hidden

    const float* srow = s_in + (size_t)row * 64;
    const float* vrow = v_in + (size_t)row * 24;

    if (tid < 24) vb[tid] = vrow[tid];
    if (tid < 16) {
        float pm = pdmean[row];
        float h = pm * enc_w1[tid] + enc_b1[tid];
        hid[tid] = silu_f(h);
    }
    __syncthreads();
    if (tid < 64) {
        float acc = enc_b2[tid];
        #pragma unroll
        for (int h = 0; h < 16; ++h) acc += hid[h] * enc_w2[tid * 16 + h];
        sc[tid] = srow[tid] + acc;
    }
    __syncthreads();

    for (int layer = 0; layer < 3; ++layer) {
        const bool act = layer < 2;
        // vector norms -> sc[64..71]
        if (tid >= 64 && tid < 72) {
            int c = tid - 64;
            float x = vb[c * 3 + 0], y = vb[c * 3 + 1], z = vb[c * 3 + 2];
            sc[64 + c] = sqrtf(x * x + y * y + z * z);
        }
        __syncthreads();

        float s_new = 0.0f;
        if (tid < 64) {
            const float* wrow = scal_w + ((size_t)layer * 64 + tid) * 72;
            float acc = scal_b[layer * 64 + tid];
            #pragma unroll
            for (int k2 = 0; k2 < 72; ++k2) acc += wrow[k2] * sc[k2];
            if (act) acc = silu_f(acc);
            s_new = acc;
        } else if (tid < 72) {
            int c = tid - 64;
            const float* wrow = gate_w + ((size_t)layer * 8 + c) * 72;
            float acc = gate_b[layer * 8 + c];
            #pragma unroll
            for (int k2 = 0; k2 < 72; ++k2) acc += wrow[k2] * sc[k2];
            g[c] = sigmoid_f(acc);
        } else if (tid < 96) {
            int idx = tid - 72;
            int o = idx / 3, xc = idx % 3;
            const float* wrow = vec_w + (size_t)layer * 64 + o * 8;
            float acc = 0.0f;
            #pragma unroll
            for (int ii = 0; ii < 8; ++ii) acc += wrow[ii] * vb[ii * 3 + xc];
            vt[idx] = acc;
        }
        __syncthreads();

        if (tid < 64) {
            sc[tid] = (layer > 0) ? (sc[tid] + s_new) : s_new;
        } else if (tid >= 72 && tid < 96) {
            int idx = tid - 72;
            int o = idx / 3;
            float val = vt[idx];
            if (act) {
                float vx = vt[o * 3 + 0], vy = vt[o * 3 + 1], vz = vt[o * 3 + 2];
                float nrm = sqrtf(vx * vx + vy * vy + vz * vz);
                val *= sigmoid_f(nrm);
            }
            val *= g[o];
            vb[idx] = (layer > 0) ? (vb[idx] + val) : val;
        }
        __syncthreads();
    }

    if (tid < 64) s_gvp[(size_t)row * 64 + tid] = sc[tid];
    if (tid < 24) v_out[(size_t)row * 24 + tid] = vb[tid];
}

// ---------------- Kernel C: QKV projection ----------------
__global__ void qkv_kernel(const float* __restrict__ s_gvp,
                           const float* __restrict__ w,
                           const float* __restrict__ bias,
                           float* __restrict__ q,
                           float* __restrict__ k,
                           float* __restrict__ v) {
    const int row = blockIdx.x;   // b*N + n
    const int tid = threadIdx.x;  // 192 threads
    __shared__ float srow[64];
    if (tid < 64) srow[tid] = s_gvp[(size_t)row * 64 + tid];
    __syncthreads();
    float acc = bias[tid];
    const float* wrow = w + (size_t)tid * 64;
    #pragma unroll
    for (int i = 0; i < 64; ++i) acc += wrow[i] * srow[i];
    int which = tid >> 6;          // 0=q 1=k 2=v
    int e = tid & 63;
    int h = e >> 4, d = e & 15;
    int b = row >> 10, n = row & 1023;
    size_t off = (((size_t)(b * HH + h)) * NN + n) * HDD + d;
    float* dst = (which == 0) ? q : (which == 1) ? k : v;
    dst[off] = acc;
}

// ---------------- Kernel D: attention with -pd bias ----------------
__global__ void attn_kernel(const float* __restrict__ q,
                            const float* __restrict__ k,
                            const float* __restrict__ v,
                            const float* __restrict__ pd,
                            float* __restrict__ o) {
    const int gid = blockIdx.x;            // (b*H + h)*N + qi
    const int qi = gid & 1023;
    const int bh = gid >> 10;
    const int b = bh >> 2;
    const int h = bh & 3;
    const int tid = threadIdx.x;           // 256 threads

    __shared__ float sc[1024];
    __shared__ float qs[16];
    __shared__ float red[4];
    __shared__ float smax_s, ssum_s;
    __shared__ float part[16][16];

    const float* qrow = q + ((size_t)bh * NN + qi) * HDD;
    if (tid < 16) qs[tid] = qrow[tid];
    __syncthreads();

    const float* kbase = k + (size_t)bh * NN * HDD;
    const float* pdrow = pd + ((size_t)(b * NN) + qi) * NN;

    float lmax = -INFINITY;
    for (int j = tid; j < NN; j += 256) {
        const float* kr = kbase + (size_t)j * HDD;
        float acc = 0.0f;
        #pragma unroll
        for (int d2 = 0; d2 < 16; ++d2) acc += qs[d2] * kr[d2];
        acc = acc * 0.25f - pdrow[j];
        sc[j] = acc;
        lmax = fmaxf(lmax, acc);
    }
    // block max
    {
        float x = lmax;
        #pragma unroll
        for (int off = 32; off > 0; off >>= 1) x = fmaxf(x, __shfl_xor(x, off, 64));
        if ((tid & 63) == 0) red[tid >> 6] = x;
        __syncthreads();
        if (tid == 0) smax_s = fmaxf(fmaxf(red[0], red[1]), fmaxf(red[2], red[3]));
        __syncthreads();
    }
    const float smax = smax_s;
    float lsum = 0.0f;
    for (int j = tid; j < NN; j += 256) {
        float e = expf(sc[j] - smax);
        sc[j] = e;
        lsum += e;
    }
    // block sum
    {
        float x = lsum;
        #pragma unroll
        for (int off = 32; off > 0; off >>= 1) x += __shfl_xor(x, off, 64);
        __syncthreads();  // protect red reuse
        if ((tid & 63) == 0) red[tid >> 6] = x;
        __syncthreads();
        if (tid == 0) ssum_s = red[0] + red[1] + red[2] + red[3];
        __syncthreads();
    }
    const float inv_sum = 1.0f / ssum_s;

    // PV: 16 groups of 16 threads; thread handles dim d over keys j = grp + 16*t
    const int d2 = tid & 15;
    const int grp = tid >> 4;
    const float* vbase = v + (size_t)bh * NN * HDD;
    float accd = 0.0f;
    for (int j = grp; j < NN; j += 16) {
        accd += sc[j] * vbase[(size_t)j * HDD + d2];
    }
    part[grp][d2] = accd;
    __syncthreads();
    if (tid < 16) {
        float t = 0.0f;
        #pragma unroll
        for (int g2 = 0; g2 < 16; ++g2) t += part[g2][tid];
        t *= inv_sum;
        o[((size_t)(b * NN + qi)) * EE + h * HDD + tid] = t;
    }
}

// ---------------- Kernel E: out projection + residual ----------------
__global__ void outproj_kernel(const float* __restrict__ s_gvp,
                               const float* __restrict__ o,
                               const float* __restrict__ w,
                               const float* __restrict__ bias,
                               float* __restrict__ s_out) {
    const int row = blockIdx.x;
    const int tid = threadIdx.x;  // 64
    __shared__ float orow[64];
    orow[tid] = o[(size_t)row * 64 + tid];
    __syncthreads();
    float acc = bias[tid];
    const float* wr = w + (size_t)tid * 64;
    #pragma unroll
    for (int i = 0; i < 64; ++i) acc += wr[i] * orow[i];
    s_out[(size_t)row * 64 + tid] = s_gvp[(size_t)row * 64 + tid] + acc;
}

extern "C" void kernel_launch(void* const* d_in, const int* in_sizes, int n_in,
                              void* d_out, int out_size, void* d_ws, size_t ws_size,
                              hipStream_t stream) {
    const float* s_in      = (const float*)d_in[0];
    const float* v_in      = (const float*)d_in[1];
    const float* coords    = (const float*)d_in[2];
    const float* enc_w1    = (const float*)d_in[3];
    const float* enc_b1    = (const float*)d_in[4];
    const float* enc_w2    = (const float*)d_in[5];
    const float* enc_b2    = (const float*)d_in[6];
    const float* scal_w    = (const float*)d_in[7];
    const float* scal_b    = (const float*)d_in[8];
    const float* vec_w     = (const float*)d_in[9];
    const float* gate_w    = (const float*)d_in[10];
    const float* gate_b    = (const float*)d_in[11];
    const float* in_proj_w = (const float*)d_in[12];
    const float* in_proj_b = (const float*)d_in[13];
    const float* out_proj_w= (const float*)d_in[14];
    const float* out_proj_b= (const float*)d_in[15];

    float* out_s  = (float*)d_out + OUT_S_OFF;
    float* out_v  = (float*)d_out + OUT_V_OFF;
    float* out_pd = (float*)d_out + OUT_PD_OFF;

    // workspace layout (floats): pdmean[8192] | s_gvp[524288] | q | k | v | o
    float* ws      = (float*)d_ws;
    float* pdmean  = ws;
    float* s_gvp   = ws + 8192;
    float* qb      = s_gvp + 524288;
    float* kb      = qb + 524288;
    float* vvb     = kb + 524288;
    float* ob      = vvb + 524288;

    const int rows = BB * NN;  // 8192

    pd_kernel<<<rows, 256, 0, stream>>>(coords, out_pd, pdmean);
    gvp_kernel<<<rows, 128, 0, stream>>>(s_in, v_in, enc_w1, enc_b1, enc_w2, enc_b2,
                                         scal_w, scal_b, vec_w, gate_w, gate_b,
                                         pdmean, s_gvp, out_v);
    qkv_kernel<<<rows, 192, 0, stream>>>(s_gvp, in_proj_w, in_proj_b, qb, kb, vvb);
    attn_kernel<<<rows * HH, 256, 0, stream>>>(qb, kb, vvb, out_pd, ob);
    outproj_kernel<<<rows, 64, 0, stream>>>(s_gvp, ob, out_proj_w, out_proj_b, out_s);
}

// Round 2
// 233.570 us; speedup vs baseline: 2.0471x; 2.0471x over previous
//
#include <hip/hip_runtime.h>
#include <hip/hip_bf16.h>
#include <math.h>

// Problem constants
#define BB 8
#define NN 1024
#define SS 64
#define VCC 8
#define EE 64
#define HH 4
#define HDD 16

// d_out layout: s (B*N*S=524288) | v (B*N*VC*3=196608) | pd (B*N*N=8388608)
#define OUT_S_OFF 0
#define OUT_V_OFF 524288
#define OUT_PD_OFF 720896

// 3-adic valuation capped at 10, zero for d==0
__device__ __forceinline__ int val3(int d) {
    int c = 0;
    unsigned ud = (unsigned)d;
    c += (ud % 3u == 0u);
    c += (ud % 9u == 0u);
    c += (ud % 27u == 0u);
    c += (ud % 81u == 0u);
    c += (ud % 243u == 0u);
    c += (ud % 729u == 0u);
    c += (ud % 2187u == 0u);
    c += (ud % 6561u == 0u);
    c += (ud % 19683u == 0u);
    c += (ud % 59049u == 0u);
    return d > 0 ? c : 0;
}

// ---------------- Kernel A: pd matrix + row means ----------------
__global__ void pd_kernel(const float* __restrict__ coords,
                          float* __restrict__ pd_out,
                          float* __restrict__ pdmean) {
    const int row = blockIdx.x;           // b*N + i
    const int b = row >> 10;
    const int i = row & 1023;
    const int tid = threadIdx.x;
    const float* cb = coords + (size_t)b * NN * 3;
    const float cx = cb[i * 3 + 0];
    const float cy = cb[i * 3 + 1];
    const float cz = cb[i * 3 + 2];
    float* prow = pd_out + (size_t)row * NN;

    // 3^(-cnt/3) = exp2(-cnt * log2(3)/3)
    const float kLog2_3_over3 = 0.5283208335737187f;

    float lsum = 0.0f;
    for (int j = tid; j < NN; j += 256) {
        float dx = cx - cb[j * 3 + 0];
        float dy = cy - cb[j * 3 + 1];
        float dz = cz - cb[j * 3 + 2];
        int d0 = (int)(fabsf(dx) * 1000.0f);
        int d1 = (int)(fabsf(dy) * 1000.0f);
        int d2 = (int)(fabsf(dz) * 1000.0f);
        int cnt = val3(d0) + val3(d1) + val3(d2);
        float p = exp2f(-(float)cnt * kLog2_3_over3);
        prow[j] = p;
        lsum += p;
    }
    // block reduce sum (4 waves)
    __shared__ float red[4];
    float x = lsum;
    #pragma unroll
    for (int off = 32; off > 0; off >>= 1) x += __shfl_xor(x, off, 64);
    if ((tid & 63) == 0) red[tid >> 6] = x;
    __syncthreads();
    if (tid == 0) pdmean[row] = (red[0] + red[1] + red[2] + red[3]) * (1.0f / 1024.0f);
}

__device__ __forceinline__ float silu_f(float x) {
    return x / (1.0f + expf(-x));
}
__device__ __forceinline__ float sigmoid_f(float x) {
    return 1.0f / (1.0f + expf(-x));
}

// ---------------- Kernel B: encoder MLP + 3 GVP layers ----------------
__global__ void gvp_kernel(const float* __restrict__ s_in,
                           const float* __restrict__ v_in,
                           const float* __restrict__ enc_w1,
                           const float* __restrict__ enc_b1,
                           const float* __restrict__ enc_w2,
                           const float* __restrict__ enc_b2,
                           const float* __restrict__ scal_w,
                           const float* __restrict__ scal_b,
                           const float* __restrict__ vec_w,
                           const float* __restrict__ gate_w,
                           const float* __restrict__ gate_b,
                           const float* __restrict__ pdmean,
                           float* __restrict__ s_gvp,
                           float* __restrict__ v_out) {
    const int row = blockIdx.x;   // b*N + n
    const int tid = threadIdx.x;  // 128 threads

    __shared__ float sc[72];      // [s | vn]
    __shared__ float vb[24];      // current v (8 channels x 3)
    __shared__ float vt[24];      // raw v_new
    __shared__ float g[8];        // gate
    __shared__ float hid[16];     // encoder hidden

    const float* srow = s_in + (size_t)row * 64;
    const float* vrow = v_in + (size_t)row * 24;

    if (tid < 24) vb[tid] = vrow[tid];
    if (tid < 16) {
        float pm = pdmean[row];
        float h = pm * enc_w1[tid] + enc_b1[tid];
        hid[tid] = silu_f(h);
    }
    __syncthreads();
    if (tid < 64) {
        float acc = enc_b2[tid];
        #pragma unroll
        for (int h = 0; h < 16; ++h) acc += hid[h] * enc_w2[tid * 16 + h];
        sc[tid] = srow[tid] + acc;
    }
    __syncthreads();

    for (int layer = 0; layer < 3; ++layer) {
        const bool act = layer < 2;
        // vector norms -> sc[64..71]
        if (tid >= 64 && tid < 72) {
            int c = tid - 64;
            float x = vb[c * 3 + 0], y = vb[c * 3 + 1], z = vb[c * 3 + 2];
            sc[64 + c] = sqrtf(x * x + y * y + z * z);
        }
        __syncthreads();

        float s_new = 0.0f;
        if (tid < 64) {
            const float* wrow = scal_w + ((size_t)layer * 64 + tid) * 72;
            float acc = scal_b[layer * 64 + tid];
            #pragma unroll
            for (int k2 = 0; k2 < 72; ++k2) acc += wrow[k2] * sc[k2];
            if (act) acc = silu_f(acc);
            s_new = acc;
        } else if (tid < 72) {
            int c = tid - 64;
            const float* wrow = gate_w + ((size_t)layer * 8 + c) * 72;
            float acc = gate_b[layer * 8 + c];
            #pragma unroll
            for (int k2 = 0; k2 < 72; ++k2) acc += wrow[k2] * sc[k2];
            g[c] = sigmoid_f(acc);
        } else if (tid < 96) {
            int idx = tid - 72;
            int o = idx / 3, xc = idx % 3;
            const float* wrow = vec_w + (size_t)layer * 64 + o * 8;
            float acc = 0.0f;
            #pragma unroll
            for (int ii = 0; ii < 8; ++ii) acc += wrow[ii] * vb[ii * 3 + xc];
            vt[idx] = acc;
        }
        __syncthreads();

        if (tid < 64) {
            sc[tid] = (layer > 0) ? (sc[tid] + s_new) : s_new;
        } else if (tid >= 72 && tid < 96) {
            int idx = tid - 72;
            int o = idx / 3;
            float val = vt[idx];
            if (act) {
                float vx = vt[o * 3 + 0], vy = vt[o * 3 + 1], vz = vt[o * 3 + 2];
                float nrm = sqrtf(vx * vx + vy * vy + vz * vz);
                val *= sigmoid_f(nrm);
            }
            val *= g[o];
            vb[idx] = (layer > 0) ? (vb[idx] + val) : val;
        }
        __syncthreads();
    }

    if (tid < 64) s_gvp[(size_t)row * 64 + tid] = sc[tid];
    if (tid < 24) v_out[(size_t)row * 24 + tid] = vb[tid];
}

// ---------------- Kernel C: QKV projection ----------------
__global__ void qkv_kernel(const float* __restrict__ s_gvp,
                           const float* __restrict__ w,
                           const float* __restrict__ bias,
                           float* __restrict__ q,
                           float* __restrict__ k,
                           float* __restrict__ v) {
    const int row = blockIdx.x;   // b*N + n
    const int tid = threadIdx.x;  // 192 threads
    __shared__ float srow[64];
    if (tid < 64) srow[tid] = s_gvp[(size_t)row * 64 + tid];
    __syncthreads();
    float acc = bias[tid];
    const float* wrow = w + (size_t)tid * 64;
    #pragma unroll
    for (int i = 0; i < 64; ++i) acc += wrow[i] * srow[i];
    int which = tid >> 6;          // 0=q 1=k 2=v
    int e = tid & 63;
    int h = e >> 4, d = e & 15;
    int b = row >> 10, n = row & 1023;
    size_t off = (((size_t)(b * HH + h)) * NN + n) * HDD + d;
    float* dst = (which == 0) ? q : (which == 1) ? k : v;
    dst[off] = acc;
}

// ---------------- Kernel D: flash-style attention with -pd bias ----------------
// Grid: (B*H) * (N/64) blocks, 256 threads.
// Thread (qg = tid>>4, kl = tid&15): owns QR=4 queries (qbase+qg*4+i),
// covers keys j = kl + 16*m within each 128-key tile.
__global__ __launch_bounds__(256, 2)
void attn_kernel(const float* __restrict__ q,
                 const float* __restrict__ k,
                 const float* __restrict__ v,
                 const float* __restrict__ pd,
                 float* __restrict__ o) {
    const int bh = blockIdx.x >> 4;        // b*H + h
    const int qt = blockIdx.x & 15;
    const int b = bh >> 2;
    const int h = bh & 3;
    const int tid = threadIdx.x;
    const int kl = tid & 15;
    const int qg = tid >> 4;
    const int qbase = qt * 64 + qg * 4;

    // padded rows (16 -> 20 floats): lane stride 80B -> 2-way bank alias (free)
    __shared__ float kt[128][20];
    __shared__ float vt[128][20];

    // Q for 4 queries -> registers (reused across all 1024 keys)
    float qreg[4][16];
    const float* qb_ = q + ((size_t)bh * NN + qbase) * HDD;
    #pragma unroll
    for (int i = 0; i < 4; ++i) {
        #pragma unroll
        for (int d = 0; d < 16; d += 4) {
            float4 t4 = *(const float4*)(qb_ + i * 16 + d);
            qreg[i][d] = t4.x; qreg[i][d+1] = t4.y; qreg[i][d+2] = t4.z; qreg[i][d+3] = t4.w;
        }
    }
    const float* pdr0 = pd + ((size_t)b * NN + qbase) * NN;

    float acc[4][16];
    #pragma unroll
    for (int i = 0; i < 4; ++i)
        #pragma unroll
        for (int d = 0; d < 16; ++d) acc[i][d] = 0.0f;
    float mrun[4] = {-INFINITY, -INFINITY, -INFINITY, -INFINITY};
    float lrun[4] = {0.0f, 0.0f, 0.0f, 0.0f};

    const float* kbase = k + (size_t)bh * NN * HDD;
    const float* vbase = v + (size_t)bh * NN * HDD;
    const float kLog2e = 1.44269504f;

    for (int tile = 0; tile < 8; ++tile) {
        __syncthreads();
        // stage K/V tile: 128 rows x 16 floats = 512 float4 each; 2 chunks/thread
        {
            const float4* kg = (const float4*)(kbase + (size_t)tile * 128 * 16);
            const float4* vg = (const float4*)(vbase + (size_t)tile * 128 * 16);
            int c0 = tid, c1 = tid + 256;
            int r0 = c0 >> 2, s0 = c0 & 3;
            int r1 = c1 >> 2, s1 = c1 & 3;
            *(float4*)&kt[r0][s0 * 4] = kg[c0];
            *(float4*)&kt[r1][s1 * 4] = kg[c1];
            *(float4*)&vt[r0][s0 * 4] = vg[c0];
            *(float4*)&vt[r1][s1 * 4] = vg[c1];
        }
        __syncthreads();

        float sc[4][8];
        #pragma unroll
        for (int m = 0; m < 8; ++m) {
            const int jt = kl + 16 * m;
            float kr[16];
            #pragma unroll
            for (int d = 0; d < 16; d += 4) {
                float4 t4 = *(const float4*)&kt[jt][d];
                kr[d] = t4.x; kr[d+1] = t4.y; kr[d+2] = t4.z; kr[d+3] = t4.w;
            }
            const int j = tile * 128 + jt;
            #pragma unroll
            for (int i = 0; i < 4; ++i) {
                float a = 0.0f;
                #pragma unroll
                for (int d = 0; d < 16; ++d) a += qreg[i][d] * kr[d];
                sc[i][m] = a * 0.25f - pdr0[(size_t)i * NN + j];
            }
        }

        // online softmax update (per query; synced across the 16 kl lanes)
        #pragma unroll
        for (int i = 0; i < 4; ++i) {
            float tmax = sc[i][0];
            #pragma unroll
            for (int m = 1; m < 8; ++m) tmax = fmaxf(tmax, sc[i][m]);
            #pragma unroll
            for (int w = 1; w < 16; w <<= 1) tmax = fmaxf(tmax, __shfl_xor(tmax, w, 16));
            float mnew = fmaxf(mrun[i], tmax);
            float scale = exp2f((mrun[i] - mnew) * kLog2e);
            mrun[i] = mnew;
            lrun[i] *= scale;
            #pragma unroll
            for (int d = 0; d < 16; ++d) acc[i][d] *= scale;
            float ls = 0.0f;
            #pragma unroll
            for (int m = 0; m < 8; ++m) {
                float p = exp2f((sc[i][m] - mnew) * kLog2e);
                sc[i][m] = p;
                ls += p;
            }
            lrun[i] += ls;
        }

        // PV accumulate
        #pragma unroll
        for (int m = 0; m < 8; ++m) {
            const int jt = kl + 16 * m;
            float vr[16];
            #pragma unroll
            for (int d = 0; d < 16; d += 4) {
                float4 t4 = *(const float4*)&vt[jt][d];
                vr[d] = t4.x; vr[d+1] = t4.y; vr[d+2] = t4.z; vr[d+3] = t4.w;
            }
            #pragma unroll
            for (int i = 0; i < 4; ++i) {
                const float p = sc[i][m];
                #pragma unroll
                for (int d = 0; d < 16; ++d) acc[i][d] += p * vr[d];
            }
        }
    }

    // final: reduce l and acc across the 16 kl lanes
    #pragma unroll
    for (int i = 0; i < 4; ++i) {
        float l = lrun[i];
        #pragma unroll
        for (int w = 1; w < 16; w <<= 1) l += __shfl_xor(l, w, 16);
        lrun[i] = l;
    }
    float outv[4] = {0.0f, 0.0f, 0.0f, 0.0f};
    #pragma unroll
    for (int i = 0; i < 4; ++i) {
        #pragma unroll
        for (int d = 0; d < 16; ++d) {
            float a = acc[i][d];
            #pragma unroll
            for (int w = 1; w < 16; w <<= 1) a += __shfl_xor(a, w, 16);
            if (kl == d) outv[i] = a;   // static d, predicated select
        }
    }
    #pragma unroll
    for (int i = 0; i < 4; ++i) {
        const int qi = qbase + i;
        o[((size_t)(b * NN + qi)) * EE + h * HDD + kl] = outv[i] / lrun[i];
    }
}

// ---------------- Kernel E: out projection + residual ----------------
__global__ void outproj_kernel(const float* __restrict__ s_gvp,
                               const float* __restrict__ o,
                               const float* __restrict__ w,
                               const float* __restrict__ bias,
                               float* __restrict__ s_out) {
    const int row = blockIdx.x;
    const int tid = threadIdx.x;  // 64
    __shared__ float orow[64];
    orow[tid] = o[(size_t)row * 64 + tid];
    __syncthreads();
    float acc = bias[tid];
    const float* wr = w + (size_t)tid * 64;
    #pragma unroll
    for (int i = 0; i < 64; ++i) acc += wr[i] * orow[i];
    s_out[(size_t)row * 64 + tid] = s_gvp[(size_t)row * 64 + tid] + acc;
}

extern "C" void kernel_launch(void* const* d_in, const int* in_sizes, int n_in,
                              void* d_out, int out_size, void* d_ws, size_t ws_size,
                              hipStream_t stream) {
    const float* s_in      = (const float*)d_in[0];
    const float* v_in      = (const float*)d_in[1];
    const float* coords    = (const float*)d_in[2];
    const float* enc_w1    = (const float*)d_in[3];
    const float* enc_b1    = (const float*)d_in[4];
    const float* enc_w2    = (const float*)d_in[5];
    const float* enc_b2    = (const float*)d_in[6];
    const float* scal_w    = (const float*)d_in[7];
    const float* scal_b    = (const float*)d_in[8];
    const float* vec_w     = (const float*)d_in[9];
    const float* gate_w    = (const float*)d_in[10];
    const float* gate_b    = (const float*)d_in[11];
    const float* in_proj_w = (const float*)d_in[12];
    const float* in_proj_b = (const float*)d_in[13];
    const float* out_proj_w= (const float*)d_in[14];
    const float* out_proj_b= (const float*)d_in[15];

    float* out_s  = (float*)d_out + OUT_S_OFF;
    float* out_v  = (float*)d_out + OUT_V_OFF;
    float* out_pd = (float*)d_out + OUT_PD_OFF;

    // workspace layout (floats): pdmean[8192] | s_gvp[524288] | q | k | v | o
    float* ws      = (float*)d_ws;
    float* pdmean  = ws;
    float* s_gvp   = ws + 8192;
    float* qb      = s_gvp + 524288;
    float* kb      = qb + 524288;
    float* vvb     = kb + 524288;
    float* ob      = vvb + 524288;

    const int rows = BB * NN;  // 8192

    pd_kernel<<<rows, 256, 0, stream>>>(coords, out_pd, pdmean);
    gvp_kernel<<<rows, 128, 0, stream>>>(s_in, v_in, enc_w1, enc_b1, enc_w2, enc_b2,
                                         scal_w, scal_b, vec_w, gate_w, gate_b,
                                         pdmean, s_gvp, out_v);
    qkv_kernel<<<rows, 192, 0, stream>>>(s_gvp, in_proj_w, in_proj_b, qb, kb, vvb);
    attn_kernel<<<BB * HH * (NN / 64), 256, 0, stream>>>(qb, kb, vvb, out_pd, ob);
    outproj_kernel<<<rows, 64, 0, stream>>>(s_gvp, ob, out_proj_w, out_proj_b, out_s);
}

// Round 3
// 212.654 us; speedup vs baseline: 2.2485x; 1.0984x over previous
//
#include <hip/hip_runtime.h>
#include <hip/hip_bf16.h>
#include <math.h>

// Problem constants
#define BB 8
#define NN 1024
#define SS 64
#define VCC 8
#define EE 64
#define HH 4
#define HDD 16

// d_out layout: s (B*N*S=524288) | v (B*N*VC*3=196608) | pd (B*N*N=8388608)
#define OUT_S_OFF 0
#define OUT_V_OFF 524288
#define OUT_PD_OFF 720896

// 3-adic valuation capped at 10, zero for d==0
__device__ __forceinline__ int val3(int d) {
    int c = 0;
    unsigned ud = (unsigned)d;
    c += (ud % 3u == 0u);
    c += (ud % 9u == 0u);
    c += (ud % 27u == 0u);
    c += (ud % 81u == 0u);
    c += (ud % 243u == 0u);
    c += (ud % 729u == 0u);
    c += (ud % 2187u == 0u);
    c += (ud % 6561u == 0u);
    c += (ud % 19683u == 0u);
    c += (ud % 59049u == 0u);
    return d > 0 ? c : 0;
}

__device__ __forceinline__ float silu_f(float x) {
    return x / (1.0f + expf(-x));
}
__device__ __forceinline__ float sigmoid_f(float x) {
    return 1.0f / (1.0f + expf(-x));
}

// ---------------- Kernel A: pd matrix + row means ----------------
// Block per (b,i) row; coords staged in LDS as SoA; 4 consecutive j per thread.
__global__ __launch_bounds__(256) void pd_kernel(const float* __restrict__ coords,
                                                 float* __restrict__ pd_out,
                                                 float* __restrict__ pdmean) {
    const int row = blockIdx.x;           // b*N + i
    const int b = row >> 10;
    const int i = row & 1023;
    const int tid = threadIdx.x;
    const float* cb = coords + (size_t)b * NN * 3;

    __shared__ float sx[1024];
    __shared__ float sy[1024];
    __shared__ float sz[1024];
    __shared__ float red[4];

    for (int idx = tid; idx < 3072; idx += 256) {
        float v = cb[idx];
        int j = idx / 3;
        int c = idx - j * 3;
        float* dst = (c == 0) ? sx : (c == 1) ? sy : sz;
        dst[j] = v;
    }
    __syncthreads();

    const float cx = sx[i], cy = sy[i], cz = sz[i];
    float* prow = pd_out + (size_t)row * NN;
    const float kLog2_3_over3 = 0.5283208335737187f;  // log2(3)/3

    const int j0 = tid * 4;
    float4 x4 = *(const float4*)&sx[j0];
    float4 y4 = *(const float4*)&sy[j0];
    float4 z4 = *(const float4*)&sz[j0];

    float p[4];
    float xs[4] = {x4.x, x4.y, x4.z, x4.w};
    float ys[4] = {y4.x, y4.y, y4.z, y4.w};
    float zs[4] = {z4.x, z4.y, z4.z, z4.w};
    float lsum = 0.0f;
    #pragma unroll
    for (int t = 0; t < 4; ++t) {
        int d0 = (int)(fabsf(cx - xs[t]) * 1000.0f);
        int d1 = (int)(fabsf(cy - ys[t]) * 1000.0f);
        int d2 = (int)(fabsf(cz - zs[t]) * 1000.0f);
        int cnt = val3(d0) + val3(d1) + val3(d2);
        p[t] = exp2f(-(float)cnt * kLog2_3_over3);
        lsum += p[t];
    }
    float4 pv = make_float4(p[0], p[1], p[2], p[3]);
    *(float4*)&prow[j0] = pv;

    // block reduce sum (4 waves)
    float x = lsum;
    #pragma unroll
    for (int off = 32; off > 0; off >>= 1) x += __shfl_xor(x, off, 64);
    if ((tid & 63) == 0) red[tid >> 6] = x;
    __syncthreads();
    if (tid == 0) pdmean[row] = (red[0] + red[1] + red[2] + red[3]) * (1.0f / 1024.0f);
}

// ---------------- Kernel B: encoder MLP + 3 GVP layers ----------------
// One 64-thread wave per block; GR rows per block; weight rows hoisted to regs.
#define GR 4
__global__ __launch_bounds__(64) void gvp_kernel(const float* __restrict__ s_in,
                           const float* __restrict__ v_in,
                           const float* __restrict__ enc_w1,
                           const float* __restrict__ enc_b1,
                           const float* __restrict__ enc_w2,
                           const float* __restrict__ enc_b2,
                           const float* __restrict__ scal_w,
                           const float* __restrict__ scal_b,
                           const float* __restrict__ vec_w,
                           const float* __restrict__ gate_w,
                           const float* __restrict__ gate_b,
                           const float* __restrict__ pdmean,
                           float* __restrict__ s_gvp,
                           float* __restrict__ v_out) {
    const int lane = threadIdx.x;          // 0..63
    const int rbase = blockIdx.x * GR;     // grid = 8192/GR

    __shared__ float sc[GR][80];           // [s(64) | vn(8)], padded
    __shared__ float vbuf[GR][24];
    __shared__ float vtb[GR][24];
    __shared__ float gg[GR][8];
    __shared__ float hid[GR][16];

    #pragma unroll
    for (int r = 0; r < GR; ++r) {
        const int row = rbase + r;
        sc[r][lane] = s_in[(size_t)row * 64 + lane];
        if (lane < 24) vbuf[r][lane] = v_in[(size_t)row * 24 + lane];
        if (lane < 16) {
            float pm = pdmean[row];
            hid[r][lane] = silu_f(pm * enc_w1[lane] + enc_b1[lane]);
        }
    }
    __syncthreads();
    // encoder layer 2: s += pf
    #pragma unroll
    for (int r = 0; r < GR; ++r) {
        float acc = enc_b2[lane];
        #pragma unroll
        for (int h = 0; h < 16; ++h) acc += hid[r][h] * enc_w2[lane * 16 + h];
        sc[r][lane] += acc;
    }
    __syncthreads();

    for (int layer = 0; layer < 3; ++layer) {
        const bool act = layer < 2;
        // phase 1: vector norms -> sc[r][64+c]
        if (lane < 8) {
            #pragma unroll
            for (int r = 0; r < GR; ++r) {
                float x = vbuf[r][lane * 3 + 0];
                float y = vbuf[r][lane * 3 + 1];
                float z = vbuf[r][lane * 3 + 2];
                sc[r][64 + lane] = sqrtf(x * x + y * y + z * z);
            }
        }
        __syncthreads();

        // phase 2: dots (scal all lanes; gate lanes<8; vec lanes<24)
        float sn[GR];
        {
            float4 w4[18];
            const float4* wr = (const float4*)(scal_w + ((size_t)layer * 64 + lane) * 72);
            #pragma unroll
            for (int k = 0; k < 18; ++k) w4[k] = wr[k];
            const float sb = scal_b[layer * 64 + lane];
            #pragma unroll
            for (int r = 0; r < GR; ++r) {
                const float4* sv = (const float4*)sc[r];
                float acc = sb;
                #pragma unroll
                for (int k = 0; k < 18; ++k) {
                    float4 s4 = sv[k];
                    acc += w4[k].x * s4.x + w4[k].y * s4.y + w4[k].z * s4.z + w4[k].w * s4.w;
                }
                sn[r] = acc;
            }
        }
        if (lane < 8) {
            float4 g4[18];
            const float4* gr_ = (const float4*)(gate_w + ((size_t)layer * 8 + lane) * 72);
            #pragma unroll
            for (int k = 0; k < 18; ++k) g4[k] = gr_[k];
            const float gb = gate_b[layer * 8 + lane];
            #pragma unroll
            for (int r = 0; r < GR; ++r) {
                const float4* sv = (const float4*)sc[r];
                float acc = gb;
                #pragma unroll
                for (int k = 0; k < 18; ++k) {
                    float4 s4 = sv[k];
                    acc += g4[k].x * s4.x + g4[k].y * s4.y + g4[k].z * s4.z + g4[k].w * s4.w;
                }
                gg[r][lane] = sigmoid_f(acc);
            }
        }
        if (lane < 24) {
            const int o = lane / 3;
            const int xc = lane - o * 3;
            const float* vw = vec_w + ((size_t)layer * 8 + o) * 8;
            float vwr[8];
            #pragma unroll
            for (int ii = 0; ii < 8; ++ii) vwr[ii] = vw[ii];
            #pragma unroll
            for (int r = 0; r < GR; ++r) {
                float acc = 0.0f;
                #pragma unroll
                for (int ii = 0; ii < 8; ++ii) acc += vwr[ii] * vbuf[r][ii * 3 + xc];
                vtb[r][lane] = acc;
            }
        }
        __syncthreads();

        // phase 3: updates
        #pragma unroll
        for (int r = 0; r < GR; ++r) {
            float val = act ? silu_f(sn[r]) : sn[r];
            sc[r][lane] = (layer > 0) ? (sc[r][lane] + val) : val;
        }
        if (lane < 24) {
            const int o = lane / 3;
            #pragma unroll
            for (int r = 0; r < GR; ++r) {
                float val = vtb[r][lane];
                if (act) {
                    float a = vtb[r][o * 3 + 0];
                    float bb2 = vtb[r][o * 3 + 1];
                    float c2 = vtb[r][o * 3 + 2];
                    val *= sigmoid_f(sqrtf(a * a + bb2 * bb2 + c2 * c2));
                }
                val *= gg[r][o];
                vbuf[r][lane] = (layer > 0) ? (vbuf[r][lane] + val) : val;
            }
        }
        __syncthreads();
    }

    #pragma unroll
    for (int r = 0; r < GR; ++r) {
        const int row = rbase + r;
        s_gvp[(size_t)row * 64 + lane] = sc[r][lane];
        if (lane < 24) v_out[(size_t)row * 24 + lane] = vbuf[r][lane];
    }
}

// ---------------- Kernel C: QKV projection (8 rows/block) ----------------
#define QROWS 8
__global__ __launch_bounds__(192) void qkv_kernel(const float* __restrict__ s_gvp,
                           const float* __restrict__ w,
                           const float* __restrict__ bias,
                           float* __restrict__ q,
                           float* __restrict__ k,
                           float* __restrict__ v) {
    const int tid = threadIdx.x;            // 0..191 = output col
    const int rbase = blockIdx.x * QROWS;   // grid 1024
    __shared__ float sl[QROWS][64];
    for (int idx = tid; idx < QROWS * 64; idx += 192)
        sl[idx >> 6][idx & 63] = s_gvp[(size_t)rbase * 64 + idx];
    __syncthreads();

    float4 w4[16];
    const float4* wr = (const float4*)(w + (size_t)tid * 64);
    #pragma unroll
    for (int kk = 0; kk < 16; ++kk) w4[kk] = wr[kk];
    const float bv = bias[tid];

    const int which = tid >> 6;
    const int e = tid & 63;
    const int h = e >> 4, d = e & 15;
    float* dst = (which == 0) ? q : (which == 1) ? k : v;

    #pragma unroll
    for (int r = 0; r < QROWS; ++r) {
        const float4* sv = (const float4*)sl[r];
        float acc = bv;
        #pragma unroll
        for (int kk = 0; kk < 16; ++kk) {
            float4 s4 = sv[kk];
            acc += w4[kk].x * s4.x + w4[kk].y * s4.y + w4[kk].z * s4.z + w4[kk].w * s4.w;
        }
        const int row = rbase + r;
        const int b = row >> 10, n = row & 1023;
        dst[(((size_t)(b * HH + h)) * NN + n) * HDD + d] = acc;
    }
}

// ---------------- Kernel D: flash-style attention with -pd bias ----------------
// Grid: (B*H) * (N/32) blocks, 256 threads.
// Thread (qg = tid>>4, kl = tid&15): owns QR=2 queries, keys j = kl + 16*m per tile.
__global__ __launch_bounds__(256, 2)
void attn_kernel(const float* __restrict__ q,
                 const float* __restrict__ k,
                 const float* __restrict__ v,
                 const float* __restrict__ pd,
                 float* __restrict__ o) {
    const int bh = blockIdx.x >> 5;        // b*H + h
    const int qt = blockIdx.x & 31;
    const int b = bh >> 2;
    const int h = bh & 3;
    const int tid = threadIdx.x;
    const int kl = tid & 15;
    const int qg = tid >> 4;
    const int qbase = qt * 32 + qg * 2;

    // padded rows (16 -> 20 floats): 2-way bank alias (free)
    __shared__ float kt[128][20];
    __shared__ float vt[128][20];

    float qreg[2][16];
    const float* qb_ = q + ((size_t)bh * NN + qbase) * HDD;
    #pragma unroll
    for (int i = 0; i < 2; ++i) {
        #pragma unroll
        for (int d = 0; d < 16; d += 4) {
            float4 t4 = *(const float4*)(qb_ + i * 16 + d);
            qreg[i][d] = t4.x; qreg[i][d+1] = t4.y; qreg[i][d+2] = t4.z; qreg[i][d+3] = t4.w;
        }
    }
    const float* pdr0 = pd + ((size_t)b * NN + qbase) * NN;

    float acc[2][16];
    #pragma unroll
    for (int i = 0; i < 2; ++i)
        #pragma unroll
        for (int d = 0; d < 16; ++d) acc[i][d] = 0.0f;
    float mrun[2] = {-INFINITY, -INFINITY};
    float lrun[2] = {0.0f, 0.0f};

    const float* kbase = k + (size_t)bh * NN * HDD;
    const float* vbase = v + (size_t)bh * NN * HDD;
    const float kLog2e = 1.44269504f;

    for (int tile = 0; tile < 8; ++tile) {
        __syncthreads();
        {
            const float4* kg = (const float4*)(kbase + (size_t)tile * 128 * 16);
            const float4* vg = (const float4*)(vbase + (size_t)tile * 128 * 16);
            int c0 = tid, c1 = tid + 256;
            int r0 = c0 >> 2, s0 = c0 & 3;
            int r1 = c1 >> 2, s1 = c1 & 3;
            *(float4*)&kt[r0][s0 * 4] = kg[c0];
            *(float4*)&kt[r1][s1 * 4] = kg[c1];
            *(float4*)&vt[r0][s0 * 4] = vg[c0];
            *(float4*)&vt[r1][s1 * 4] = vg[c1];
        }
        __syncthreads();

        float sc[2][8];
        #pragma unroll
        for (int m = 0; m < 8; ++m) {
            const int jt = kl + 16 * m;
            float kr[16];
            #pragma unroll
            for (int d = 0; d < 16; d += 4) {
                float4 t4 = *(const float4*)&kt[jt][d];
                kr[d] = t4.x; kr[d+1] = t4.y; kr[d+2] = t4.z; kr[d+3] = t4.w;
            }
            const int j = tile * 128 + jt;
            #pragma unroll
            for (int i = 0; i < 2; ++i) {
                float a = 0.0f;
                #pragma unroll
                for (int d = 0; d < 16; ++d) a += qreg[i][d] * kr[d];
                sc[i][m] = a * 0.25f - pdr0[(size_t)i * NN + j];
            }
        }

        #pragma unroll
        for (int i = 0; i < 2; ++i) {
            float tmax = sc[i][0];
            #pragma unroll
            for (int m = 1; m < 8; ++m) tmax = fmaxf(tmax, sc[i][m]);
            #pragma unroll
            for (int w = 1; w < 16; w <<= 1) tmax = fmaxf(tmax, __shfl_xor(tmax, w, 16));
            float mnew = fmaxf(mrun[i], tmax);
            float scale = exp2f((mrun[i] - mnew) * kLog2e);
            mrun[i] = mnew;
            lrun[i] *= scale;
            #pragma unroll
            for (int d = 0; d < 16; ++d) acc[i][d] *= scale;
            float ls = 0.0f;
            #pragma unroll
            for (int m = 0; m < 8; ++m) {
                float p = exp2f((sc[i][m] - mnew) * kLog2e);
                sc[i][m] = p;
                ls += p;
            }
            lrun[i] += ls;
        }

        #pragma unroll
        for (int m = 0; m < 8; ++m) {
            const int jt = kl + 16 * m;
            float vr[16];
            #pragma unroll
            for (int d = 0; d < 16; d += 4) {
                float4 t4 = *(const float4*)&vt[jt][d];
                vr[d] = t4.x; vr[d+1] = t4.y; vr[d+2] = t4.z; vr[d+3] = t4.w;
            }
            #pragma unroll
            for (int i = 0; i < 2; ++i) {
                const float p = sc[i][m];
                #pragma unroll
                for (int d = 0; d < 16; ++d) acc[i][d] += p * vr[d];
            }
        }
    }

    #pragma unroll
    for (int i = 0; i < 2; ++i) {
        float l = lrun[i];
        #pragma unroll
        for (int w = 1; w < 16; w <<= 1) l += __shfl_xor(l, w, 16);
        lrun[i] = l;
    }
    float outv[2] = {0.0f, 0.0f};
    #pragma unroll
    for (int i = 0; i < 2; ++i) {
        #pragma unroll
        for (int d = 0; d < 16; ++d) {
            float a = acc[i][d];
            #pragma unroll
            for (int w = 1; w < 16; w <<= 1) a += __shfl_xor(a, w, 16);
            if (kl == d) outv[i] = a;
        }
    }
    #pragma unroll
    for (int i = 0; i < 2; ++i) {
        const int qi = qbase + i;
        o[((size_t)(b * NN + qi)) * EE + h * HDD + kl] = outv[i] / lrun[i];
    }
}

// ---------------- Kernel E: out projection + residual (16 rows/block) ----------------
#define OROWS 16
__global__ __launch_bounds__(256) void outproj_kernel(const float* __restrict__ s_gvp,
                               const float* __restrict__ o,
                               const float* __restrict__ w,
                               const float* __restrict__ bias,
                               float* __restrict__ s_out) {
    const int tid = threadIdx.x;
    const int col = tid & 63;
    const int wq = tid >> 6;                // wave id 0..3
    const int rbase = blockIdx.x * OROWS;   // grid 512
    __shared__ float ol[OROWS][64];
    for (int idx = tid; idx < OROWS * 64; idx += 256)
        ol[idx >> 6][idx & 63] = o[(size_t)rbase * 64 + idx];
    __syncthreads();

    float4 w4[16];
    const float4* wr = (const float4*)(w + (size_t)col * 64);
    #pragma unroll
    for (int kk = 0; kk < 16; ++kk) w4[kk] = wr[kk];
    const float bv = bias[col];

    #pragma unroll
    for (int rr = 0; rr < OROWS / 4; ++rr) {
        const int r = wq * (OROWS / 4) + rr;
        const float4* sv = (const float4*)ol[r];
        float acc = bv;
        #pragma unroll
        for (int kk = 0; kk < 16; ++kk) {
            float4 s4 = sv[kk];
            acc += w4[kk].x * s4.x + w4[kk].y * s4.y + w4[kk].z * s4.z + w4[kk].w * s4.w;
        }
        const int row = rbase + r;
        s_out[(size_t)row * 64 + col] = s_gvp[(size_t)row * 64 + col] + acc;
    }
}

extern "C" void kernel_launch(void* const* d_in, const int* in_sizes, int n_in,
                              void* d_out, int out_size, void* d_ws, size_t ws_size,
                              hipStream_t stream) {
    const float* s_in      = (const float*)d_in[0];
    const float* v_in      = (const float*)d_in[1];
    const float* coords    = (const float*)d_in[2];
    const float* enc_w1    = (const float*)d_in[3];
    const float* enc_b1    = (const float*)d_in[4];
    const float* enc_w2    = (const float*)d_in[5];
    const float* enc_b2    = (const float*)d_in[6];
    const float* scal_w    = (const float*)d_in[7];
    const float* scal_b    = (const float*)d_in[8];
    const float* vec_w     = (const float*)d_in[9];
    const float* gate_w    = (const float*)d_in[10];
    const float* gate_b    = (const float*)d_in[11];
    const float* in_proj_w = (const float*)d_in[12];
    const float* in_proj_b = (const float*)d_in[13];
    const float* out_proj_w= (const float*)d_in[14];
    const float* out_proj_b= (const float*)d_in[15];

    float* out_s  = (float*)d_out + OUT_S_OFF;
    float* out_v  = (float*)d_out + OUT_V_OFF;
    float* out_pd = (float*)d_out + OUT_PD_OFF;

    // workspace layout (floats): pdmean[8192] | s_gvp[524288] | q | k | v | o
    float* ws      = (float*)d_ws;
    float* pdmean  = ws;
    float* s_gvp   = ws + 8192;
    float* qb      = s_gvp + 524288;
    float* kb      = qb + 524288;
    float* vvb     = kb + 524288;
    float* ob      = vvb + 524288;

    const int rows = BB * NN;  // 8192

    pd_kernel<<<rows, 256, 0, stream>>>(coords, out_pd, pdmean);
    gvp_kernel<<<rows / GR, 64, 0, stream>>>(s_in, v_in, enc_w1, enc_b1, enc_w2, enc_b2,
                                             scal_w, scal_b, vec_w, gate_w, gate_b,
                                             pdmean, s_gvp, out_v);
    qkv_kernel<<<rows / QROWS, 192, 0, stream>>>(s_gvp, in_proj_w, in_proj_b, qb, kb, vvb);
    attn_kernel<<<BB * HH * (NN / 32), 256, 0, stream>>>(qb, kb, vvb, out_pd, ob);
    outproj_kernel<<<rows / OROWS, 256, 0, stream>>>(s_gvp, ob, out_proj_w, out_proj_b, out_s);
}